// Round 4
// baseline (25.870 us; speedup 1.0000x reference)
//
#include <hip/hip_runtime.h>

// SparseDualFlow closed form (see round-1 analysis): out = K * relu(d) with
// K from a compile-time simulation of the 20-step momentum-prox recurrence
// (linear in the state; ReLU never clamps for d>0, flow==0 for d<=0).
//
// Non-temporal output stores (write-once stream) so the 64 MB input stays
// L3-resident across graph replays and writes stream to HBM. Uses a clang
// native vector type: __builtin_nontemporal_store rejects HIP_vector_type.

typedef float floatx4 __attribute__((ext_vector_type(4)));

constexpr float compute_K() {
    double a = 0.0, f = 0.0;
    for (int t = 0; t < 20; ++t) {
        const double am = 0.9 * a;
        const double g  = 2.0 * (f - am) - 1.0;   // gradient coeff of d
        a = am + 0.01 * g;
        f = f - a;                                 // relu never clamps for d>0
    }
    return (float)f;
}

__global__ __launch_bounds__(256) void sdf_kernel(const float* __restrict__ dd,
                                                  float* __restrict__ out,
                                                  int n) {
    constexpr float K = compute_K();

    const int tid    = blockIdx.x * blockDim.x + threadIdx.x;
    const int stride = gridDim.x * blockDim.x;
    const int n4     = n >> 2;

    const floatx4* __restrict__ dd4  = reinterpret_cast<const floatx4*>(dd);
    floatx4* __restrict__       out4 = reinterpret_cast<floatx4*>(out);

    for (int i = tid; i < n4; i += stride) {
        const floatx4 dv = dd4[i];
        floatx4 o;
        o.x = K * fmaxf(dv.x, 0.0f);
        o.y = K * fmaxf(dv.y, 0.0f);
        o.z = K * fmaxf(dv.z, 0.0f);
        o.w = K * fmaxf(dv.w, 0.0f);
        __builtin_nontemporal_store(o, &out4[i]);   // stream past L2/L3
    }

    // Scalar tail (n = 2^24 so normally empty; kept for safety).
    const int tail = n4 << 2;
    for (int i = tail + tid; i < n; i += stride) {
        __builtin_nontemporal_store(K * fmaxf(dd[i], 0.0f), &out[i]);
    }
}

extern "C" void kernel_launch(void* const* d_in, const int* in_sizes, int n_in,
                              void* d_out, int out_size, void* d_ws, size_t ws_size,
                              hipStream_t stream) {
    const float* dd = (const float*)d_in[0];
    float* out      = (float*)d_out;
    const int n     = in_sizes[0];

    const int block = 256;
    const int n4    = n >> 2;
    int grid = (n4 + block - 1) / block;
    if (grid > 2048) grid = 2048;   // grid-stride; ~8 float4 per thread at n=2^24
    if (grid < 1) grid = 1;

    sdf_kernel<<<grid, block, 0, stream>>>(dd, out, n);
}

// Round 5
// 24.624 us; speedup vs baseline: 1.0506x; 1.0506x over previous
//
#include <hip/hip_runtime.h>

// SparseDualFlow closed form: out = K * relu(d), K from compile-time
// simulation of the 20-step momentum-prox recurrence (linear in state;
// ReLU never clamps for d>0, flow stays 0 for d<=0).
//
// This round: ILP restructure — 4 independent float4 loads in flight per
// thread (no serial load->store->load chain), exact-sized grid (4096 blocks,
// 2x the waves of the capped grid-stride version), nt stores retained.

typedef float floatx4 __attribute__((ext_vector_type(4)));

constexpr float compute_K() {
    double a = 0.0, f = 0.0;
    for (int t = 0; t < 20; ++t) {
        const double am = 0.9 * a;
        const double g  = 2.0 * (f - am) - 1.0;   // gradient coeff of d
        a = am + 0.01 * g;
        f = f - a;                                 // relu never clamps for d>0
    }
    return (float)f;
}

#define UNROLL 4

__global__ __launch_bounds__(256) void sdf_kernel(const float* __restrict__ dd,
                                                  float* __restrict__ out,
                                                  int n4) {
    constexpr float K = compute_K();

    const floatx4* __restrict__ dd4  = reinterpret_cast<const floatx4*>(dd);
    floatx4* __restrict__       out4 = reinterpret_cast<floatx4*>(out);

    const int base = blockIdx.x * (blockDim.x * UNROLL) + threadIdx.x;

    // Issue all 4 independent loads first (coalesced: lanes contiguous,
    // batches strided by blockDim), then compute + nt-store.
    floatx4 v[UNROLL];
    int idx[UNROLL];
    #pragma unroll
    for (int k = 0; k < UNROLL; ++k) {
        idx[k] = base + k * blockDim.x;
        if (idx[k] < n4) v[k] = dd4[idx[k]];
    }
    #pragma unroll
    for (int k = 0; k < UNROLL; ++k) {
        if (idx[k] < n4) {
            floatx4 o;
            o.x = K * fmaxf(v[k].x, 0.0f);
            o.y = K * fmaxf(v[k].y, 0.0f);
            o.z = K * fmaxf(v[k].z, 0.0f);
            o.w = K * fmaxf(v[k].w, 0.0f);
            __builtin_nontemporal_store(o, &out4[idx[k]]);
        }
    }
}

// Scalar tail kernel for n not divisible by 4 (n = 2^24 here, so unused).
__global__ void sdf_tail(const float* __restrict__ dd, float* __restrict__ out,
                         int start, int n) {
    constexpr float K = compute_K();
    const int i = start + blockIdx.x * blockDim.x + threadIdx.x;
    if (i < n) out[i] = K * fmaxf(dd[i], 0.0f);
}

extern "C" void kernel_launch(void* const* d_in, const int* in_sizes, int n_in,
                              void* d_out, int out_size, void* d_ws, size_t ws_size,
                              hipStream_t stream) {
    const float* dd = (const float*)d_in[0];
    float* out      = (float*)d_out;
    const int n     = in_sizes[0];

    const int block = 256;
    const int n4    = n >> 2;
    const int per_block = block * UNROLL;           // float4s per block
    int grid = (n4 + per_block - 1) / per_block;    // 4096 at n = 2^24
    if (grid < 1) grid = 1;

    sdf_kernel<<<grid, block, 0, stream>>>(dd, out, n4);

    const int tail_start = n4 << 2;
    if (tail_start < n) {
        const int tail_n = n - tail_start;
        sdf_tail<<<(tail_n + 255) / 256, 256, 0, stream>>>(dd, out, tail_start, n);
    }
}